// Round 2
// baseline (2529.024 us; speedup 1.0000x reference)
//
#include <hip/hip_runtime.h>
#include <cstdint>
#include <cstddef>

#define N_USER 100000
#define N_ITEM 50000
#define CDIM   128
#define NEDGE  600000

typedef __bf16 bf16_t;
typedef bf16_t bfvec8 __attribute__((ext_vector_type(8)));
typedef float  f32x4  __attribute__((ext_vector_type(4)));

// ---------------------------------------------------------------------------
// GEMM: Y[M,128] = act(X[M,128] @ W[128,128] + bias). fp32 in/out, bf16 MFMA
// with fp32 accumulate. Block = 256 thr (4 waves), 128 rows per block
// (2 strips of 16 rows per wave). W converted to bf16 and staged transposed
// in LDS (Wt[n][k], row stride 136 elems) so B-fragments are contiguous.
// MFMA 16x16x32_bf16 layouts (HW-verified, guide §3):
//   A[m=lane&15][k=quad*8+j], B[k=quad*8+j][n=lane&15],
//   D reg r -> row=quad*4+r, col=lane&15.
// In-place (Y==X) is safe: each block reads/writes only its own 128 rows;
// OOB lanes clamp to row 0 but their results are discarded by the M guard.
// ---------------------------------------------------------------------------
#define LDW 136

template <bool RELU>
__global__ __launch_bounds__(256) void gemm128(
    const float* X,
    const float* __restrict__ W,
    const float* __restrict__ B,
    float* Y, int M)
{
    __shared__ bf16_t Wt[128 * LDW];
    const int tid = threadIdx.x;

    // Stage W (fp32 [k][n]) transposed to bf16 Wt[n][k].
    {
        const f32x4* W4 = reinterpret_cast<const f32x4*>(W);
        #pragma unroll
        for (int i = 0; i < 16; ++i) {
            int cidx = i * 256 + tid;        // float4 chunk id, 4096 total
            int base = cidx * 4;             // element index
            int k  = base >> 7;
            int n0 = base & 127;
            f32x4 v = W4[cidx];
            #pragma unroll
            for (int j = 0; j < 4; ++j) Wt[(n0 + j) * LDW + k] = (bf16_t)v[j];
        }
    }
    __syncthreads();

    const int wave = tid >> 6, lane = tid & 63;
    const int quad = lane >> 4, ln16 = lane & 15;

    #pragma unroll
    for (int s = 0; s < 2; ++s) {
        int row0 = blockIdx.x * 128 + s * 64 + wave * 16;   // 16-row strip
        int arow = row0 + ln16;
        int arow_c = arow < M ? arow : 0;

        // A fragments: 4 K-chunks of 32; load fp32, convert to bf16.
        bfvec8 a[4];
        const float* xp = X + (size_t)arow_c * CDIM + quad * 8;
        #pragma unroll
        for (int kc = 0; kc < 4; ++kc) {
            f32x4 lo = *reinterpret_cast<const f32x4*>(xp + kc * 32);
            f32x4 hi = *reinterpret_cast<const f32x4*>(xp + kc * 32 + 4);
            #pragma unroll
            for (int j = 0; j < 4; ++j) {
                a[kc][j]     = (bf16_t)lo[j];
                a[kc][j + 4] = (bf16_t)hi[j];
            }
        }

        f32x4 acc[8];
        #pragma unroll
        for (int t = 0; t < 8; ++t) acc[t] = (f32x4){0.f, 0.f, 0.f, 0.f};

        #pragma unroll
        for (int t = 0; t < 8; ++t) {
            const bf16_t* wp = &Wt[(t * 16 + ln16) * LDW + quad * 8];
            #pragma unroll
            for (int kc = 0; kc < 4; ++kc) {
                bfvec8 b = *reinterpret_cast<const bfvec8*>(wp + kc * 32);
                acc[t] = __builtin_amdgcn_mfma_f32_16x16x32_bf16(a[kc], b, acc[t], 0, 0, 0);
            }
        }

        if (row0 < M) {
            #pragma unroll
            for (int t = 0; t < 8; ++t) {
                int col = t * 16 + ln16;
                float bias = B[col];
                #pragma unroll
                for (int r = 0; r < 4; ++r) {
                    int row = row0 + quad * 4 + r;
                    if (row < M) {
                        float v = acc[t][r] + bias;
                        if (RELU) v = v > 0.f ? v : 0.f;
                        Y[(size_t)row * CDIM + col] = v;
                    }
                }
            }
        }
    }
}

// ---------------------------------------------------------------------------
// zero-fill (replaces hipMemsetAsync; float4 per thread)
// ---------------------------------------------------------------------------
__global__ __launch_bounds__(256) void zero_k(float4* __restrict__ p, int n4)
{
    int i = blockIdx.x * 256 + threadIdx.x;
    if (i < n4) p[i] = make_float4(0.f, 0.f, 0.f, 0.f);
}

// ---------------------------------------------------------------------------
// Scatter-add (segment_sum): one wave per edge, lane handles 2 channels.
// ---------------------------------------------------------------------------
__global__ __launch_bounds__(256) void scatter_add(
    const float* __restrict__ F,
    const int* __restrict__ edges,     // [2, E]: src row then dst row
    float* __restrict__ agg, int nE)
{
    int wave = threadIdx.x >> 6, lane = threadIdx.x & 63;
    int e = blockIdx.x * 4 + wave;
    if (e >= nE) return;
    int src = edges[e];
    int dst = edges[nE + e];
    float2 v = *reinterpret_cast<const float2*>(F + (size_t)src * CDIM + lane * 2);
    float* p = agg + (size_t)dst * CDIM + lane * 2;
    atomicAdd(p,     v.x);
    atomicAdd(p + 1, v.y);
}

// ---------------------------------------------------------------------------
// in-place combine: t = (1+eps)*x + t     (t already holds the scatter sum)
// ---------------------------------------------------------------------------
__global__ __launch_bounds__(256) void combine_k(
    const float* __restrict__ x,
    const float* __restrict__ epsp,
    float* __restrict__ t, int n4)     // n4 = rows*32
{
    int i = blockIdx.x * 256 + threadIdx.x;
    if (i >= n4) return;
    float s = 1.f + *epsp;
    float4 xv = reinterpret_cast<const float4*>(x)[i];
    float4 tv = reinterpret_cast<float4*>(t)[i];
    tv.x = s * xv.x + tv.x;
    tv.y = s * xv.y + tv.y;
    tv.z = s * xv.z + tv.z;
    tv.w = s * xv.w + tv.w;
    reinterpret_cast<float4*>(t)[i] = tv;
}

// ---------------------------------------------------------------------------
// LayerNorm over 128 channels + affine + ReLU. One wave per row, fp32.
// ---------------------------------------------------------------------------
__global__ __launch_bounds__(256) void ln_relu(
    const float* __restrict__ H,
    const float* __restrict__ G,
    const float* __restrict__ Bb,
    float* __restrict__ out, int rows)
{
    int wave = threadIdx.x >> 6, lane = threadIdx.x & 63;
    int row = blockIdx.x * 4 + wave;
    if (row >= rows) return;
    float2 v = reinterpret_cast<const float2*>(H + (size_t)row * CDIM)[lane];
    float s = v.x + v.y;
    #pragma unroll
    for (int m = 32; m >= 1; m >>= 1) s += __shfl_xor(s, m, 64);
    float mean = s * (1.f / 128.f);
    float d0 = v.x - mean, d1 = v.y - mean;
    float q = d0 * d0 + d1 * d1;
    #pragma unroll
    for (int m = 32; m >= 1; m >>= 1) q += __shfl_xor(q, m, 64);
    float rs = rsqrtf(q * (1.f / 128.f) + 1e-5f);
    float2 g = reinterpret_cast<const float2*>(G)[lane];
    float2 b = reinterpret_cast<const float2*>(Bb)[lane];
    float y0 = d0 * rs * g.x + b.x;
    float y1 = d1 * rs * g.y + b.y;
    y0 = y0 > 0.f ? y0 : 0.f;
    y1 = y1 > 0.f ? y1 : 0.f;
    float2 o; o.x = y0; o.y = y1;
    reinterpret_cast<float2*>(out + (size_t)row * CDIM)[lane] = o;
}

// ---------------------------------------------------------------------------
extern "C" void kernel_launch(void* const* d_in, const int* in_sizes, int n_in,
                              void* d_out, int out_size, void* d_ws, size_t ws_size,
                              hipStream_t stream)
{
    const float* x_user = (const float*)d_in[0];
    const float* x_item = (const float*)d_in[1];
    const float* W_init = (const float*)d_in[2];
    const float* b_init = (const float*)d_in[3];
    const float* mlp_W  = (const float*)d_in[4];
    const float* mlp_b  = (const float*)d_in[5];
    const float* eps    = (const float*)d_in[6];
    const float* ln_g   = (const float*)d_in[7];
    const float* ln_b   = (const float*)d_in[8];
    const int* edge_ui  = (const int*)d_in[9];
    const int* edge_iu  = (const int*)d_in[10];

    // xu/xi live in d_out (final LN writes land there anyway).
    float* xu = (float*)d_out;                      // [N_USER,128]
    float* xi = xu + (size_t)N_USER * CDIM;         // [N_ITEM,128]
    // tu/ti in ws: double as fp32 scatter accumulators. ws use = 76.8 MB.
    float* tu = (float*)d_ws;                       // [N_USER,128]
    float* ti = tu + (size_t)N_USER * CDIM;         // [N_ITEM,128]

    const int gU = (N_USER + 127) / 128;   // 782
    const int gI = (N_ITEM + 127) / 128;   // 391
    const int gE = (NEDGE + 3) / 4;        // 150000
    const int nAll4 = (N_USER + N_ITEM) * (CDIM / 4);   // 4.8M float4

    // Initial projection (no activation)
    gemm128<false><<<gU, 256, 0, stream>>>(x_user, W_init,         b_init,       xu, N_USER);
    gemm128<false><<<gI, 256, 0, stream>>>(x_item, W_init + 16384, b_init + 128, xi, N_ITEM);

    for (int l = 0; l < 2; ++l) {
        zero_k<<<(nAll4 + 255) / 256, 256, 0, stream>>>((float4*)tu, nAll4);

        scatter_add<<<gE, 256, 0, stream>>>(xu, edge_ui, ti, NEDGE);  // user->item
        scatter_add<<<gE, 256, 0, stream>>>(xi, edge_iu, tu, NEDGE);  // item->user

        // combine in place: item uses eps[l,0], user uses eps[l,1]
        combine_k<<<(N_ITEM * 32 + 255) / 256, 256, 0, stream>>>(xi, eps + (l * 2 + 0), ti, N_ITEM * 32);
        combine_k<<<(N_USER * 32 + 255) / 256, 256, 0, stream>>>(xu, eps + (l * 2 + 1), tu, N_USER * 32);

        // item MLP (in-place ping: ti -> ti -> ti)
        gemm128<true><<<gI, 256, 0, stream>>>(ti, mlp_W + (size_t)((l * 2 + 0) * 2 + 0) * 16384,
                                              mlp_b + ((l * 2 + 0) * 2 + 0) * 128, ti, N_ITEM);
        gemm128<true><<<gI, 256, 0, stream>>>(ti, mlp_W + (size_t)((l * 2 + 0) * 2 + 1) * 16384,
                                              mlp_b + ((l * 2 + 0) * 2 + 1) * 128, ti, N_ITEM);
        // user MLP
        gemm128<true><<<gU, 256, 0, stream>>>(tu, mlp_W + (size_t)((l * 2 + 1) * 2 + 0) * 16384,
                                              mlp_b + ((l * 2 + 1) * 2 + 0) * 128, tu, N_USER);
        gemm128<true><<<gU, 256, 0, stream>>>(tu, mlp_W + (size_t)((l * 2 + 1) * 2 + 1) * 16384,
                                              mlp_b + ((l * 2 + 1) * 2 + 1) * 128, tu, N_USER);

        // LayerNorm+ReLU: node type 0 = user (ln_g[l,0]), 1 = item (ln_g[l,1])
        ln_relu<<<(N_USER + 3) / 4, 256, 0, stream>>>(tu, ln_g + (l * 2 + 0) * 128, ln_b + (l * 2 + 0) * 128, xu, N_USER);
        ln_relu<<<(N_ITEM + 3) / 4, 256, 0, stream>>>(ti, ln_g + (l * 2 + 1) * 128, ln_b + (l * 2 + 1) * 128, xi, N_ITEM);
    }
}

// Round 3
// 845.592 us; speedup vs baseline: 2.9908x; 2.9908x over previous
//
#include <hip/hip_runtime.h>
#include <cstdint>
#include <cstddef>

#define N_USER 100000
#define N_ITEM 50000
#define CDIM   128
#define NEDGE  600000
#define N_SEG  (N_ITEM + N_USER)          // item segments first, then user
#define NB_SCAN ((N_SEG + 255) / 256)     // 586 scan blocks

typedef __bf16 bf16_t;
typedef bf16_t bfvec8 __attribute__((ext_vector_type(8)));
typedef float  f32x4  __attribute__((ext_vector_type(4)));

// ---------------------------------------------------------------------------
// GEMM: Y[M,128] = act(X[M,128] @ W[128,128] + bias). fp32 in/out, bf16 MFMA
// with fp32 accumulate. Block = 256 thr (4 waves), 128 rows per block.
// W converted to bf16 and staged transposed in LDS (Wt[n][k], stride 136).
// MFMA 16x16x32_bf16: A[m=lane&15][k=quad*8+j], B[k=quad*8+j][n=lane&15],
// D reg r -> row=quad*4+r, col=lane&15. In-place safe (row-disjoint blocks).
// ---------------------------------------------------------------------------
#define LDW 136

template <bool RELU>
__global__ __launch_bounds__(256) void gemm128(
    const float* X,
    const float* __restrict__ W,
    const float* __restrict__ B,
    float* Y, int M)
{
    __shared__ bf16_t Wt[128 * LDW];
    const int tid = threadIdx.x;
    {
        const f32x4* W4 = reinterpret_cast<const f32x4*>(W);
        #pragma unroll
        for (int i = 0; i < 16; ++i) {
            int cidx = i * 256 + tid;
            int base = cidx * 4;
            int k  = base >> 7;
            int n0 = base & 127;
            f32x4 v = W4[cidx];
            #pragma unroll
            for (int j = 0; j < 4; ++j) Wt[(n0 + j) * LDW + k] = (bf16_t)v[j];
        }
    }
    __syncthreads();

    const int wave = tid >> 6, lane = tid & 63;
    const int quad = lane >> 4, ln16 = lane & 15;

    #pragma unroll
    for (int s = 0; s < 2; ++s) {
        int row0 = blockIdx.x * 128 + s * 64 + wave * 16;
        int arow = row0 + ln16;
        int arow_c = arow < M ? arow : 0;

        bfvec8 a[4];
        const float* xp = X + (size_t)arow_c * CDIM + quad * 8;
        #pragma unroll
        for (int kc = 0; kc < 4; ++kc) {
            f32x4 lo = *reinterpret_cast<const f32x4*>(xp + kc * 32);
            f32x4 hi = *reinterpret_cast<const f32x4*>(xp + kc * 32 + 4);
            #pragma unroll
            for (int j = 0; j < 4; ++j) {
                a[kc][j]     = (bf16_t)lo[j];
                a[kc][j + 4] = (bf16_t)hi[j];
            }
        }

        f32x4 acc[8];
        #pragma unroll
        for (int t = 0; t < 8; ++t) acc[t] = (f32x4){0.f, 0.f, 0.f, 0.f};

        #pragma unroll
        for (int t = 0; t < 8; ++t) {
            const bf16_t* wp = &Wt[(t * 16 + ln16) * LDW + quad * 8];
            #pragma unroll
            for (int kc = 0; kc < 4; ++kc) {
                bfvec8 b = *reinterpret_cast<const bfvec8*>(wp + kc * 32);
                acc[t] = __builtin_amdgcn_mfma_f32_16x16x32_bf16(a[kc], b, acc[t], 0, 0, 0);
            }
        }

        if (row0 < M) {
            #pragma unroll
            for (int t = 0; t < 8; ++t) {
                int col = t * 16 + ln16;
                float bias = B[col];
                #pragma unroll
                for (int r = 0; r < 4; ++r) {
                    int row = row0 + quad * 4 + r;
                    if (row < M) {
                        float v = acc[t][r] + bias;
                        if (RELU) v = v > 0.f ? v : 0.f;
                        Y[(size_t)row * CDIM + col] = v;
                    }
                }
            }
        }
    }
}

// ---------------------------------------------------------------------------
// CSR build: zero -> histogram -> block scan -> block-sum scan -> add+cursor
// -> bucket fill. Segments: [0,N_ITEM) items (dst of edge_ui),
// [N_ITEM,N_SEG) users (dst of edge_iu).
// ---------------------------------------------------------------------------
__global__ __launch_bounds__(256) void zero_i32(int* __restrict__ p, int n)
{
    int i = blockIdx.x * 256 + threadIdx.x;
    if (i < n) p[i] = 0;
}

__global__ __launch_bounds__(256) void hist_k(
    const int* __restrict__ edge_ui, const int* __restrict__ edge_iu,
    int* __restrict__ deg)
{
    int i = blockIdx.x * 256 + threadIdx.x;
    if (i >= NEDGE) return;
    atomicAdd(&deg[edge_ui[NEDGE + i]], 1);
    atomicAdd(&deg[N_ITEM + edge_iu[NEDGE + i]], 1);
}

// per-block exclusive scan over 256-elem chunks; bsum[blk] = chunk total
__global__ __launch_bounds__(256) void block_scan(
    int* __restrict__ off, int* __restrict__ bsum, int n)
{
    __shared__ int sh[256];
    int tid = threadIdx.x;
    int i = blockIdx.x * 256 + tid;
    int v = (i < n) ? off[i] : 0;
    sh[tid] = v;
    __syncthreads();
    #pragma unroll
    for (int d = 1; d < 256; d <<= 1) {
        int t = (tid >= d) ? sh[tid - d] : 0;
        __syncthreads();
        sh[tid] += t;
        __syncthreads();
    }
    if (i < n) off[i] = sh[tid] - v;          // exclusive within block
    if (tid == 255) bsum[blockIdx.x] = sh[255];
}

// single-block exclusive scan of block sums; bsum[NB_SCAN] = grand total
__global__ __launch_bounds__(1024) void scan_bsums(int* __restrict__ bsum)
{
    __shared__ int sh[1024];
    int tid = threadIdx.x;
    int v = (tid < NB_SCAN) ? bsum[tid] : 0;
    sh[tid] = v;
    __syncthreads();
    #pragma unroll
    for (int d = 1; d < 1024; d <<= 1) {
        int t = (tid >= d) ? sh[tid - d] : 0;
        __syncthreads();
        sh[tid] += t;
        __syncthreads();
    }
    if (tid < NB_SCAN) bsum[tid] = sh[tid] - v;
    if (tid == 1023) bsum[NB_SCAN] = sh[1023];
}

__global__ __launch_bounds__(256) void add_offsets(
    int* __restrict__ off, const int* __restrict__ bsum,
    int* __restrict__ cursor, int n)
{
    int i = blockIdx.x * 256 + threadIdx.x;
    if (i < n) {
        int o = off[i] + bsum[i >> 8];
        off[i] = o;
        cursor[i] = o;
    } else if (i == n) {
        off[n] = bsum[NB_SCAN];
    }
}

__global__ __launch_bounds__(256) void fill_k(
    const int* __restrict__ edge_ui, const int* __restrict__ edge_iu,
    int* __restrict__ cursor, int* __restrict__ srcbuf)
{
    int i = blockIdx.x * 256 + threadIdx.x;
    if (i >= NEDGE) return;
    {
        int dst = edge_ui[NEDGE + i];
        int slot = atomicAdd(&cursor[dst], 1);
        srcbuf[slot] = edge_ui[i];
    }
    {
        int dst = edge_iu[NEDGE + i];
        int slot = atomicAdd(&cursor[N_ITEM + dst], 1);
        srcbuf[slot] = edge_iu[i];
    }
}

// ---------------------------------------------------------------------------
// Gather-aggregate + fused GIN combine: out[n] = (1+eps)*x[n] + sum_{e} F[src]
// One wave per destination node; lane holds 2 channels (float2).
// ---------------------------------------------------------------------------
__global__ __launch_bounds__(256) void gather_agg(
    const float* __restrict__ F,      // neighbor features
    const float* __restrict__ X,      // self features
    const float* __restrict__ epsp,
    const int* __restrict__ off,      // offsets for this node type (n+1)
    const int* __restrict__ srcbuf,
    float* __restrict__ out, int n)
{
    int wave = threadIdx.x >> 6, lane = threadIdx.x & 63;
    int node = blockIdx.x * 4 + wave;
    if (node >= n) return;
    int start = off[node], end = off[node + 1];
    float s = 1.f + *epsp;
    float2 x = *reinterpret_cast<const float2*>(X + (size_t)node * CDIM + lane * 2);
    float ax = s * x.x, ay = s * x.y;

    int e = start;
    for (; e + 4 <= end; e += 4) {
        int s0 = srcbuf[e + 0], s1 = srcbuf[e + 1];
        int s2 = srcbuf[e + 2], s3 = srcbuf[e + 3];
        float2 v0 = *reinterpret_cast<const float2*>(F + (size_t)s0 * CDIM + lane * 2);
        float2 v1 = *reinterpret_cast<const float2*>(F + (size_t)s1 * CDIM + lane * 2);
        float2 v2 = *reinterpret_cast<const float2*>(F + (size_t)s2 * CDIM + lane * 2);
        float2 v3 = *reinterpret_cast<const float2*>(F + (size_t)s3 * CDIM + lane * 2);
        ax += (v0.x + v1.x) + (v2.x + v3.x);
        ay += (v0.y + v1.y) + (v2.y + v3.y);
    }
    for (; e < end; ++e) {
        int s0 = srcbuf[e];
        float2 v = *reinterpret_cast<const float2*>(F + (size_t)s0 * CDIM + lane * 2);
        ax += v.x; ay += v.y;
    }
    float2 o; o.x = ax; o.y = ay;
    *reinterpret_cast<float2*>(out + (size_t)node * CDIM + lane * 2) = o;
}

// ---------------------------------------------------------------------------
// LayerNorm over 128 channels + affine + ReLU. One wave per row, fp32.
// ---------------------------------------------------------------------------
__global__ __launch_bounds__(256) void ln_relu(
    const float* __restrict__ H,
    const float* __restrict__ G,
    const float* __restrict__ Bb,
    float* __restrict__ out, int rows)
{
    int wave = threadIdx.x >> 6, lane = threadIdx.x & 63;
    int row = blockIdx.x * 4 + wave;
    if (row >= rows) return;
    float2 v = reinterpret_cast<const float2*>(H + (size_t)row * CDIM)[lane];
    float s = v.x + v.y;
    #pragma unroll
    for (int m = 32; m >= 1; m >>= 1) s += __shfl_xor(s, m, 64);
    float mean = s * (1.f / 128.f);
    float d0 = v.x - mean, d1 = v.y - mean;
    float q = d0 * d0 + d1 * d1;
    #pragma unroll
    for (int m = 32; m >= 1; m >>= 1) q += __shfl_xor(q, m, 64);
    float rs = rsqrtf(q * (1.f / 128.f) + 1e-5f);
    float2 g = reinterpret_cast<const float2*>(G)[lane];
    float2 b = reinterpret_cast<const float2*>(Bb)[lane];
    float y0 = d0 * rs * g.x + b.x;
    float y1 = d1 * rs * g.y + b.y;
    y0 = y0 > 0.f ? y0 : 0.f;
    y1 = y1 > 0.f ? y1 : 0.f;
    float2 o; o.x = y0; o.y = y1;
    reinterpret_cast<float2*>(out + (size_t)row * CDIM)[lane] = o;
}

// ---------------------------------------------------------------------------
extern "C" void kernel_launch(void* const* d_in, const int* in_sizes, int n_in,
                              void* d_out, int out_size, void* d_ws, size_t ws_size,
                              hipStream_t stream)
{
    const float* x_user = (const float*)d_in[0];
    const float* x_item = (const float*)d_in[1];
    const float* W_init = (const float*)d_in[2];
    const float* b_init = (const float*)d_in[3];
    const float* mlp_W  = (const float*)d_in[4];
    const float* mlp_b  = (const float*)d_in[5];
    const float* eps    = (const float*)d_in[6];
    const float* ln_g   = (const float*)d_in[7];
    const float* ln_b   = (const float*)d_in[8];
    const int* edge_ui  = (const int*)d_in[9];
    const int* edge_iu  = (const int*)d_in[10];

    // xu/xi live in d_out (final LN writes land there anyway).
    float* xu = (float*)d_out;                      // [N_USER,128]
    float* xi = xu + (size_t)N_USER * CDIM;         // [N_ITEM,128]

    // workspace layout
    float* tu = (float*)d_ws;                       // 51.2 MB
    float* ti = tu + (size_t)N_USER * CDIM;         // 25.6 MB
    int* off_all = (int*)(ti + (size_t)N_ITEM * CDIM);  // N_SEG+1
    int* cursor  = off_all + (N_SEG + 4);               // N_SEG
    int* bsum    = cursor + N_SEG;                      // NB_SCAN+1
    int* srcbuf  = bsum + (NB_SCAN + 2);                // 2*NEDGE

    const int gU = (N_USER + 127) / 128;
    const int gI = (N_ITEM + 127) / 128;
    const int gSeg = (N_SEG + 256) / 256;           // covers i == N_SEG too
    const int gE = (NEDGE + 255) / 256;

    // ---- CSR build (edge list is a fixed input; rebuilt every call) ----
    zero_i32<<<(N_SEG + 255) / 256, 256, 0, stream>>>(off_all, N_SEG);
    hist_k<<<gE, 256, 0, stream>>>(edge_ui, edge_iu, off_all);
    block_scan<<<NB_SCAN, 256, 0, stream>>>(off_all, bsum, N_SEG);
    scan_bsums<<<1, 1024, 0, stream>>>(bsum);
    add_offsets<<<gSeg, 256, 0, stream>>>(off_all, bsum, cursor, N_SEG);
    fill_k<<<gE, 256, 0, stream>>>(edge_ui, edge_iu, cursor, srcbuf);

    // ---- initial projection ----
    gemm128<false><<<gU, 256, 0, stream>>>(x_user, W_init,         b_init,       xu, N_USER);
    gemm128<false><<<gI, 256, 0, stream>>>(x_item, W_init + 16384, b_init + 128, xi, N_ITEM);

    for (int l = 0; l < 2; ++l) {
        // gather + combine: items (eps[l,0]) from xu; users (eps[l,1]) from xi
        gather_agg<<<(N_ITEM + 3) / 4, 256, 0, stream>>>(
            xu, xi, eps + (l * 2 + 0), off_all,          srcbuf, ti, N_ITEM);
        gather_agg<<<(N_USER + 3) / 4, 256, 0, stream>>>(
            xi, xu, eps + (l * 2 + 1), off_all + N_ITEM, srcbuf, tu, N_USER);

        // item MLP (in-place), then user MLP (in-place)
        gemm128<true><<<gI, 256, 0, stream>>>(ti, mlp_W + (size_t)((l * 2 + 0) * 2 + 0) * 16384,
                                              mlp_b + ((l * 2 + 0) * 2 + 0) * 128, ti, N_ITEM);
        gemm128<true><<<gI, 256, 0, stream>>>(ti, mlp_W + (size_t)((l * 2 + 0) * 2 + 1) * 16384,
                                              mlp_b + ((l * 2 + 0) * 2 + 1) * 128, ti, N_ITEM);
        gemm128<true><<<gU, 256, 0, stream>>>(tu, mlp_W + (size_t)((l * 2 + 1) * 2 + 0) * 16384,
                                              mlp_b + ((l * 2 + 1) * 2 + 0) * 128, tu, N_USER);
        gemm128<true><<<gU, 256, 0, stream>>>(tu, mlp_W + (size_t)((l * 2 + 1) * 2 + 1) * 16384,
                                              mlp_b + ((l * 2 + 1) * 2 + 1) * 128, tu, N_USER);

        // LayerNorm+ReLU: node type 0 = user, 1 = item
        ln_relu<<<(N_USER + 3) / 4, 256, 0, stream>>>(tu, ln_g + (l * 2 + 0) * 128, ln_b + (l * 2 + 0) * 128, xu, N_USER);
        ln_relu<<<(N_ITEM + 3) / 4, 256, 0, stream>>>(ti, ln_g + (l * 2 + 1) * 128, ln_b + (l * 2 + 1) * 128, xi, N_ITEM);
    }
}